// Round 8
// baseline (292.533 us; speedup 1.0000x reference)
//
#include <hip/hip_runtime.h>
#include <hip/hip_bf16.h>

#define N_TOK 4096
#define D_DIM 512
#define E_NUM 8
#define H_DIM 2048
#define RB_NUM 256   // router blocks (16 tokens each)
#define TP_NUM 8704  // transpose tiles: 4096 wg + 4096 wu + 512 wd

typedef __attribute__((ext_vector_type(8))) short short8;
typedef __attribute__((ext_vector_type(4))) float f32x4;

__device__ inline short f2bs(float f) {
  __hip_bfloat16 h = __float2bfloat16(f);
  return *reinterpret_cast<short*>(&h);
}

// async global->LDS, 16 B per lane; lds dest is wave-uniform base + lane*16
__device__ inline void llds16(const short* g, short* l) {
  __builtin_amdgcn_global_load_lds(
      (const __attribute__((address_space(1))) void*)g,
      (__attribute__((address_space(3))) void*)l, 16, 0, 0);
}

// ---------- fused prep+router ----------
// blocks [0,256): router (16 tokens each, 16 lanes/token, atomic-free buckets)
// blocks [256, 256+8704): 64r x 32c transpose tiles (wg/wu/wd)
// block 256+8704: zero down-tile counters
__global__ void __launch_bounds__(256) prep_router_kernel(
    const float* __restrict__ wg, const float* __restrict__ wu,
    const float* __restrict__ wd, const float* __restrict__ x,
    const float* __restrict__ wr, short* __restrict__ wgb,
    short* __restrict__ wub, short* __restrict__ wdb, short* __restrict__ xb,
    int* __restrict__ cnt_blk, int* __restrict__ tok_bkt,
    float* __restrict__ p_bkt, float* __restrict__ psum_blk,
    int* __restrict__ tile_cnt) {
  int u = blockIdx.x;
  int tid = threadIdx.x;

  if (u >= RB_NUM) {
    int v = u - RB_NUM;
    if (v >= TP_NUM) {  // zero down-tile counters
      if (tid < 128) tile_cnt[tid] = 0;
      return;
    }
    // ---- 64r x 32c transpose-convert, int-packed bf16 writes ----
    __shared__ float tbuf[64][33];
    const float* in;
    short* op;
    int R, C, c0, r0;
    if (v < 8192) {
      in = (v < 4096) ? wg : wu;
      op = (v < 4096) ? wgb : wub;
      int w = v & 4095;
      R = D_DIM; C = E_NUM * H_DIM;
      c0 = (w & 511) * 32; r0 = (w >> 9) * 64;
    } else {
      in = wd; op = wdb;
      int w = v - 8192;
      R = H_DIM; C = D_DIM;
      c0 = (w & 15) * 32; r0 = (w >> 4) * 64;
    }
    int tx = tid & 31, ty = tid >> 5;
#pragma unroll
    for (int i = 0; i < 8; ++i)
      tbuf[ty + 8 * i][tx] = in[(size_t)(r0 + ty + 8 * i) * C + c0 + tx];
    __syncthreads();
#pragma unroll
    for (int i = 0; i < 4; ++i) {
      int cl = ty + 8 * i;
      unsigned lo = (unsigned short)f2bs(tbuf[2 * tx][cl]);
      unsigned hi = (unsigned short)f2bs(tbuf[2 * tx + 1][cl]);
      ((int*)op)[(((size_t)(c0 + cl) * R) + r0) / 2 + tx] = (int)(lo | (hi << 16));
    }
    return;
  }

  // ---- router part: 16 tokens, 16 lanes per token ----
  __shared__ float wr_t[E_NUM * D_DIM];  // [e][d], 16 KB
  __shared__ int h_cnt[E_NUM];
  __shared__ float psh[E_NUM];
  int rb = u;
  for (int i = tid; i < D_DIM * E_NUM; i += 256)
    wr_t[(i & 7) * D_DIM + (i >> 3)] = wr[i];  // wr is [d][e]
  if (tid < E_NUM) { h_cnt[tid] = 0; psh[tid] = 0.f; }
  __syncthreads();

  int r = tid >> 4, pp = tid & 15;
  int t = rb * 16 + r;
  const float* xr0 = x + (size_t)t * D_DIM;
  short* xw0 = xb + (size_t)t * D_DIM;
  float acc[8] = {0, 0, 0, 0, 0, 0, 0, 0};
#pragma unroll
  for (int j = 0; j < 8; ++j) {
    int d = j * 64 + pp * 4;  // 16 lanes cover 64 consecutive floats
    float4 xv = *(const float4*)(xr0 + d);
    short4 o;
    o.x = f2bs(xv.x); o.y = f2bs(xv.y); o.z = f2bs(xv.z); o.w = f2bs(xv.w);
    *(short4*)(xw0 + d) = o;
#pragma unroll
    for (int e = 0; e < 8; ++e) {
      float4 w = *(const float4*)&wr_t[e * D_DIM + d];
      acc[e] += xv.x * w.x + xv.y * w.y + xv.z * w.z + xv.w * w.w;
    }
  }
#pragma unroll
  for (int e = 0; e < 8; ++e) {
    acc[e] += __shfl_xor(acc[e], 1);
    acc[e] += __shfl_xor(acc[e], 2);
    acc[e] += __shfl_xor(acc[e], 4);
    acc[e] += __shfl_xor(acc[e], 8);
  }

  if (pp == 0) {
    float m = acc[0];
#pragma unroll
    for (int e = 1; e < 8; ++e) m = fmaxf(m, acc[e]);
    float p[8], s = 0.f;
#pragma unroll
    for (int e = 0; e < 8; ++e) { p[e] = expf(acc[e] - m); s += p[e]; }
    float inv = 1.f / s;
#pragma unroll
    for (int e = 0; e < 8; ++e) {
      p[e] *= inv;
      atomicAdd(&psh[e], p[e]);  // LDS scope
    }
    int i0 = 0;
#pragma unroll
    for (int e = 1; e < 8; ++e) if (p[e] > p[i0]) i0 = e;
    int i1 = (i0 == 0) ? 1 : 0;
#pragma unroll
    for (int e = 0; e < 8; ++e) if (e != i0 && p[e] > p[i1]) i1 = e;
    float ps = p[i0] + p[i1] + 1e-10f;
    float q0 = p[i0] / ps, q1 = p[i1] / ps;
    int l0 = atomicAdd(&h_cnt[i0], 1);  // LDS scope
    int l1 = atomicAdd(&h_cnt[i1], 1);
    tok_bkt[i0 * (RB_NUM * 16) + rb * 16 + l0] = t * 2 + 0;
    p_bkt[i0 * (RB_NUM * 16) + rb * 16 + l0] = q0;
    tok_bkt[i1 * (RB_NUM * 16) + rb * 16 + l1] = t * 2 + 1;
    p_bkt[i1 * (RB_NUM * 16) + rb * 16 + l1] = q1;
  }
  __syncthreads();
  if (tid < E_NUM) {
    cnt_blk[rb * 8 + tid] = h_cnt[tid];   // plain stores, fully owned
    psum_blk[rb * 8 + tid] = psh[tid];
  }
}

// ---------- grouped gate/up GEMM (256 tok x 64 h tile, G+U fused) ----------
// z==8: single loss block; z<8: expert GEMM with wave-shuffle-scan row lookup
__global__ void __launch_bounds__(256, 2) moe_gateup_kernel(
    const short* __restrict__ xb, const short* __restrict__ wg,
    const short* __restrict__ wu, const int* __restrict__ cnt_blk,
    const int* __restrict__ tok_bkt, const float* __restrict__ p_bkt,
    const float* __restrict__ psum_blk, short* __restrict__ act,
    float* __restrict__ out_loss) {
  int e = blockIdx.z;
  int tid = threadIdx.x;

  if (e == 8) {  // load-balance loss
    if (blockIdx.x || blockIdx.y) return;
    __shared__ float sums[8];
    if (tid < 8) sums[tid] = 0.f;
    __syncthreads();
#pragma unroll
    for (int ee = 0; ee < 8; ++ee)
      atomicAdd(&sums[ee], psum_blk[tid * 8 + ee]);
    __syncthreads();
    if (tid == 0) {
      float lb = 0.f;
#pragma unroll
      for (int ee = 0; ee < 8; ++ee) {
        float pe = sums[ee] / (float)N_TOK;
        lb += pe * logf(pe * 8.f + 1e-10f);
      }
      out_loss[0] = 8.f * lb;
    }
    return;
  }

  __shared__ __align__(16) short As[256 * 64];   // 32 KB
  __shared__ __align__(16) short Bgs[64 * 64];   // 8 KB
  __shared__ __align__(16) short Bus[64 * 64];   // 8 KB
  __shared__ int scan[256];
  __shared__ int wsum[4];
  __shared__ int s_row[256];
  __shared__ float s_pr[256];

  int lane = tid & 63, wid = tid >> 6;

  // inclusive prefix scan via wave shuffles (1 barrier)
  {
    int c = cnt_blk[tid * 8 + e];
#pragma unroll
    for (int ofs = 1; ofs < 64; ofs <<= 1) {
      int v = __shfl_up(c, ofs);
      if (lane >= ofs) c += v;
    }
    if (lane == 63) wsum[wid] = c;
    __syncthreads();
    int pre = 0;
#pragma unroll
    for (int w = 0; w < 4; ++w) pre += (w < wid) ? wsum[w] : 0;
    scan[tid] = c + pre;
    __syncthreads();
  }
  int n_e = scan[255];
  int rt = blockIdx.y;
  if (rt * 256 >= n_e) return;
  int h0 = blockIdx.x * 64;

  {
    int r = rt * 256 + tid;
    int srow = -1;
    float spr = 0.f;
    if (r < n_e) {
      int lo = 0, hi = 255;  // smallest b with scan[b] > r
      while (lo < hi) { int mid = (lo + hi) >> 1; if (scan[mid] > r) hi = mid; else lo = mid + 1; }
      int prev = lo ? scan[lo - 1] : 0;
      int idx = e * (RB_NUM * 16) + lo * 16 + (r - prev);
      srow = tok_bkt[idx];
      spr = p_bkt[idx];
    }
    s_row[tid] = srow;
    s_pr[tid] = spr;
  }
  __syncthreads();

  int cg = (lane & 7) ^ (lane >> 3);  // swizzled global chunk for this lane
  const short* baseA[8];
  const short* baseB[4];
  short* ldsA = As + (size_t)wid * 64 * 64;
  short* ldsB;
#pragma unroll
  for (int jj = 0; jj < 8; ++jj) {
    int r = wid * 64 + jj * 8 + (lane >> 3);
    int row = s_row[r];
    int t = (row < 0) ? 0 : (row >> 1);
    baseA[jj] = xb + (size_t)t * D_DIM + cg * 8;
  }
  {
    const short* wB = ((wid & 2) ? wu : wg) + (size_t)e * H_DIM * D_DIM;
    int rb = (wid & 1) * 32;
    ldsB = ((wid & 2) ? Bus : Bgs) + rb * 64;
#pragma unroll
    for (int jj = 0; jj < 4; ++jj) {
      int h = h0 + rb + jj * 8 + (lane >> 3);
      baseB[jj] = wB + (size_t)h * D_DIM + cg * 8;
    }
  }

  int ml = lane & 15, quad = lane >> 4;
  int m0w = wid * 64;
  f32x4 accG[4][4], accU[4][4];
#pragma unroll
  for (int mf = 0; mf < 4; ++mf)
#pragma unroll
    for (int nf = 0; nf < 4; ++nf) {
      accG[mf][nf] = (f32x4){0, 0, 0, 0};
      accU[mf][nf] = (f32x4){0, 0, 0, 0};
    }

  for (int kt = 0; kt < D_DIM / 64; ++kt) {
    int kb = kt * 64;
#pragma unroll
    for (int jj = 0; jj < 8; ++jj)
      llds16(baseA[jj] + kb, ldsA + jj * 8 * 64);
#pragma unroll
    for (int jj = 0; jj < 4; ++jj)
      llds16(baseB[jj] + kb, ldsB + jj * 8 * 64);
    __syncthreads();
#pragma unroll
    for (int ks = 0; ks < 2; ++ks) {
      int cs = ((quad + ks * 4) ^ (ml & 7)) * 8;
      short8 a[4], bg[4], bu[4];
#pragma unroll
      for (int mf = 0; mf < 4; ++mf)
        a[mf] = *(const short8*)&As[(m0w + mf * 16 + ml) * 64 + cs];
#pragma unroll
      for (int nf = 0; nf < 4; ++nf) {
        bg[nf] = *(const short8*)&Bgs[(nf * 16 + ml) * 64 + cs];
        bu[nf] = *(const short8*)&Bus[(nf * 16 + ml) * 64 + cs];
      }
#pragma unroll
      for (int mf = 0; mf < 4; ++mf)
#pragma unroll
        for (int nf = 0; nf < 4; ++nf) {
          accG[mf][nf] = __builtin_amdgcn_mfma_f32_16x16x32_bf16(a[mf], bg[nf], accG[mf][nf], 0, 0, 0);
          accU[mf][nf] = __builtin_amdgcn_mfma_f32_16x16x32_bf16(a[mf], bu[nf], accU[mf][nf], 0, 0, 0);
        }
    }
    __syncthreads();
  }

#pragma unroll
  for (int mf = 0; mf < 4; ++mf)
#pragma unroll
    for (int r = 0; r < 4; ++r) {
      int rl = m0w + mf * 16 + quad * 4 + r;
      int arow = s_row[rl];
      if (arow >= 0) {
        float pr = s_pr[rl];
#pragma unroll
        for (int nf = 0; nf < 4; ++nf) {
          float g = accG[mf][nf][r], u = accU[mf][nf][r];
          float val = pr * (g / (1.f + __expf(-g))) * u;
          act[(size_t)arow * H_DIM + h0 + nf * 16 + ml] = f2bs(val);
        }
      }
    }
}

// ---------- down GEMM + fused last-block split-K reduction ----------
// 128x128 tile, Ksplit=4 across blockIdx.z; partials + per-tile counter;
// last-arriving block sums the 4 partials (ksb order) and writes out
__global__ void __launch_bounds__(256, 3) down_kernel(
    const short* __restrict__ act, const short* __restrict__ wd,
    float* __restrict__ partial, int* __restrict__ tile_cnt,
    float* __restrict__ out) {
  __shared__ __align__(16) short As[128 * 64];  // 16 KB
  __shared__ __align__(16) short Bs[128 * 64];  // 16 KB
  __shared__ int lastf;
  int d0 = blockIdx.x * 128;
  int t0 = blockIdx.y * 128;
  int ksb = blockIdx.z;  // kt range [ksb*16, ksb*16+16)
  int tid = threadIdx.x, lane = tid & 63, wid = tid >> 6;
  int cg = (lane & 7) ^ (lane >> 3);

  const short* baseA[4];
  const short* baseB[4];
  short* ldsA = As + (size_t)wid * 32 * 64;
  short* ldsB = Bs + (size_t)wid * 32 * 64;
#pragma unroll
  for (int jj = 0; jj < 4; ++jj) {
    int r = wid * 32 + jj * 8 + (lane >> 3);
    baseA[jj] = act + (size_t)(2 * (t0 + r)) * H_DIM + cg * 8;
    int d = d0 + wid * 32 + jj * 8 + (lane >> 3);
    baseB[jj] = wd + (size_t)d * H_DIM + cg * 8;
  }

  int ml = lane & 15, quad = lane >> 4;
  int m0w = (wid & 1) * 64, n0w = (wid >> 1) * 64;
  f32x4 acc[4][4];
#pragma unroll
  for (int mf = 0; mf < 4; ++mf)
#pragma unroll
    for (int nf = 0; nf < 4; ++nf) acc[mf][nf] = (f32x4){0, 0, 0, 0};

  for (int kt = ksb * 16; kt < ksb * 16 + 16; ++kt) {
    size_t offA = (size_t)(kt & 1) * H_DIM + (kt >> 1) * 64;
    int offB = (kt >> 1) * 64;
#pragma unroll
    for (int jj = 0; jj < 4; ++jj) {
      llds16(baseA[jj] + offA, ldsA + jj * 8 * 64);
      llds16(baseB[jj] + offB, ldsB + jj * 8 * 64);
    }
    __syncthreads();
#pragma unroll
    for (int ks = 0; ks < 2; ++ks) {
      int cs = ((quad + ks * 4) ^ (ml & 7)) * 8;
      short8 a[4], b[4];
#pragma unroll
      for (int mf = 0; mf < 4; ++mf)
        a[mf] = *(const short8*)&As[(m0w + mf * 16 + ml) * 64 + cs];
#pragma unroll
      for (int nf = 0; nf < 4; ++nf)
        b[nf] = *(const short8*)&Bs[(n0w + nf * 16 + ml) * 64 + cs];
#pragma unroll
      for (int mf = 0; mf < 4; ++mf)
#pragma unroll
        for (int nf = 0; nf < 4; ++nf)
          acc[mf][nf] = __builtin_amdgcn_mfma_f32_16x16x32_bf16(a[mf], b[nf], acc[mf][nf], 0, 0, 0);
    }
    __syncthreads();
  }

  float* pout = partial + (size_t)ksb * N_TOK * D_DIM;
#pragma unroll
  for (int mf = 0; mf < 4; ++mf)
#pragma unroll
    for (int r = 0; r < 4; ++r) {
      int t = t0 + m0w + mf * 16 + quad * 4 + r;
#pragma unroll
      for (int nf = 0; nf < 4; ++nf)
        pout[(size_t)t * D_DIM + d0 + n0w + nf * 16 + ml] = acc[mf][nf][r];
    }

  // last block of this (x,y) tile sums the 4 partials and writes out
  __threadfence();  // release partial stores (device scope)
  if (tid == 0)
    lastf = (atomicAdd(&tile_cnt[blockIdx.y * 4 + blockIdx.x], 1) == 3);
  __syncthreads();
  if (!lastf) return;
  __threadfence();  // acquire: partials from other XCDs now visible
  const int Q = N_TOK * D_DIM / 4;
  const float4* p4 = (const float4*)partial;
#pragma unroll
  for (int i = 0; i < 16; ++i) {
    int q = tid + 256 * i;                      // tile-local float4 index
    int t = t0 + (q >> 5), dc = (q & 31) * 4;   // 32 float4 per 128-d row
    int gi = t * (D_DIM / 4) + (d0 + dc) / 4;
    float4 a = p4[gi], b = p4[gi + Q], c = p4[gi + 2 * Q], d = p4[gi + 3 * Q];
    float4 rr = {a.x + b.x + c.x + d.x, a.y + b.y + c.y + d.y,
                 a.z + b.z + c.z + d.z, a.w + b.w + c.w + d.w};
    ((float4*)out)[gi] = rr;
  }
}

extern "C" void kernel_launch(void* const* d_in, const int* in_sizes, int n_in,
                              void* d_out, int out_size, void* d_ws, size_t ws_size,
                              hipStream_t stream) {
  const float* x = (const float*)d_in[0];
  const float* wr = (const float*)d_in[1];
  const float* wg = (const float*)d_in[2];
  const float* wu = (const float*)d_in[3];
  const float* wd = (const float*)d_in[4];
  float* out = (float*)d_out;

  char* ws = (char*)d_ws;
  size_t off = 0;
  auto alloc = [&](size_t bytes) {
    char* p = ws + off;
    off += (bytes + 255) & ~(size_t)255;
    return p;
  };
  short* xb = (short*)alloc((size_t)N_TOK * D_DIM * 2);
  short* wgb = (short*)alloc((size_t)E_NUM * H_DIM * D_DIM * 2);  // [e*H+h][d]
  short* wub = (short*)alloc((size_t)E_NUM * H_DIM * D_DIM * 2);
  short* wdb = (short*)alloc((size_t)D_DIM * H_DIM * 2);          // [d][h]
  short* act = (short*)alloc((size_t)N_TOK * 2 * H_DIM * 2);      // [2t+slot][H]
  float* partial = (float*)alloc((size_t)4 * N_TOK * D_DIM * 4);  // split-K partials
  int* cnt_blk = (int*)alloc((size_t)RB_NUM * E_NUM * 4);
  int* tok_bkt = (int*)alloc((size_t)E_NUM * RB_NUM * 16 * 4);
  float* p_bkt = (float*)alloc((size_t)E_NUM * RB_NUM * 16 * 4);
  float* psum_blk = (float*)alloc((size_t)RB_NUM * E_NUM * 4);
  int* tile_cnt = (int*)alloc(128 * 4);

  prep_router_kernel<<<RB_NUM + TP_NUM + 1, 256, 0, stream>>>(
      wg, wu, wd, x, wr, wgb, wub, wdb, xb, cnt_blk, tok_bkt, p_bkt, psum_blk,
      tile_cnt);
  moe_gateup_kernel<<<dim3(H_DIM / 64, N_TOK / 256, E_NUM + 1), 256, 0, stream>>>(
      xb, wgb, wub, cnt_blk, tok_bkt, p_bkt, psum_blk, act,
      out + (size_t)N_TOK * D_DIM);
  down_kernel<<<dim3(D_DIM / 128, N_TOK / 128, 4), 256, 0, stream>>>(
      act, wdb, partial, tile_cnt, out);
}

// Round 9
// 209.737 us; speedup vs baseline: 1.3948x; 1.3948x over previous
//
#include <hip/hip_runtime.h>
#include <hip/hip_bf16.h>

#define N_TOK 4096
#define D_DIM 512
#define E_NUM 8
#define H_DIM 2048
#define RB_NUM 256   // router blocks (16 tokens each)
#define TP_NUM 8704  // transpose tiles: 4096 wg + 4096 wu + 512 wd

typedef __attribute__((ext_vector_type(8))) short short8;
typedef __attribute__((ext_vector_type(4))) float f32x4;

__device__ inline short f2bs(float f) {
  __hip_bfloat16 h = __float2bfloat16(f);
  return *reinterpret_cast<short*>(&h);
}

// async global->LDS, 16 B per lane; lds dest is wave-uniform base + lane*16
__device__ inline void llds16(const short* g, short* l) {
  __builtin_amdgcn_global_load_lds(
      (const __attribute__((address_space(1))) void*)g,
      (__attribute__((address_space(3))) void*)l, 16, 0, 0);
}

// ---------- fused prep+router ----------
// blocks [0,256): router (16 tokens each, 16 lanes/token, atomic-free buckets)
// blocks [256, 256+8704): 64r x 32c transpose tiles (wg/wu/wd)
__global__ void __launch_bounds__(256) prep_router_kernel(
    const float* __restrict__ wg, const float* __restrict__ wu,
    const float* __restrict__ wd, const float* __restrict__ x,
    const float* __restrict__ wr, short* __restrict__ wgb,
    short* __restrict__ wub, short* __restrict__ wdb, short* __restrict__ xb,
    int* __restrict__ cnt_blk, int* __restrict__ tok_bkt,
    float* __restrict__ p_bkt, float* __restrict__ psum_blk) {
  int u = blockIdx.x;
  int tid = threadIdx.x;

  if (u >= RB_NUM) {
    // ---- 64r x 32c transpose-convert, int-packed bf16 writes ----
    __shared__ float tbuf[64][33];
    int v = u - RB_NUM;
    const float* in;
    short* op;
    int R, C, c0, r0;
    if (v < 8192) {
      in = (v < 4096) ? wg : wu;
      op = (v < 4096) ? wgb : wub;
      int w = v & 4095;
      R = D_DIM; C = E_NUM * H_DIM;
      c0 = (w & 511) * 32; r0 = (w >> 9) * 64;
    } else {
      in = wd; op = wdb;
      int w = v - 8192;
      R = H_DIM; C = D_DIM;
      c0 = (w & 15) * 32; r0 = (w >> 4) * 64;
    }
    int tx = tid & 31, ty = tid >> 5;
#pragma unroll
    for (int i = 0; i < 8; ++i)
      tbuf[ty + 8 * i][tx] = in[(size_t)(r0 + ty + 8 * i) * C + c0 + tx];
    __syncthreads();
#pragma unroll
    for (int i = 0; i < 4; ++i) {
      int cl = ty + 8 * i;
      unsigned lo = (unsigned short)f2bs(tbuf[2 * tx][cl]);
      unsigned hi = (unsigned short)f2bs(tbuf[2 * tx + 1][cl]);
      ((int*)op)[(((size_t)(c0 + cl) * R) + r0) / 2 + tx] = (int)(lo | (hi << 16));
    }
    return;
  }

  // ---- router part: 16 tokens, 16 lanes per token ----
  __shared__ float wr_t[E_NUM * D_DIM];  // [e][d], 16 KB
  __shared__ int h_cnt[E_NUM];
  __shared__ float psh[E_NUM];
  int rb = u;
  for (int i = tid; i < D_DIM * E_NUM; i += 256)
    wr_t[(i & 7) * D_DIM + (i >> 3)] = wr[i];  // wr is [d][e]
  if (tid < E_NUM) { h_cnt[tid] = 0; psh[tid] = 0.f; }
  __syncthreads();

  int r = tid >> 4, pp = tid & 15;
  int t = rb * 16 + r;
  const float* xr0 = x + (size_t)t * D_DIM;
  short* xw0 = xb + (size_t)t * D_DIM;
  float acc[8] = {0, 0, 0, 0, 0, 0, 0, 0};
#pragma unroll
  for (int j = 0; j < 8; ++j) {
    int d = j * 64 + pp * 4;  // 16 lanes cover 64 consecutive floats
    float4 xv = *(const float4*)(xr0 + d);
    short4 o;
    o.x = f2bs(xv.x); o.y = f2bs(xv.y); o.z = f2bs(xv.z); o.w = f2bs(xv.w);
    *(short4*)(xw0 + d) = o;
#pragma unroll
    for (int e = 0; e < 8; ++e) {
      float4 w = *(const float4*)&wr_t[e * D_DIM + d];
      acc[e] += xv.x * w.x + xv.y * w.y + xv.z * w.z + xv.w * w.w;
    }
  }
#pragma unroll
  for (int e = 0; e < 8; ++e) {
    acc[e] += __shfl_xor(acc[e], 1);
    acc[e] += __shfl_xor(acc[e], 2);
    acc[e] += __shfl_xor(acc[e], 4);
    acc[e] += __shfl_xor(acc[e], 8);
  }

  if (pp == 0) {
    float m = acc[0];
#pragma unroll
    for (int e = 1; e < 8; ++e) m = fmaxf(m, acc[e]);
    float p[8], s = 0.f;
#pragma unroll
    for (int e = 0; e < 8; ++e) { p[e] = expf(acc[e] - m); s += p[e]; }
    float inv = 1.f / s;
#pragma unroll
    for (int e = 0; e < 8; ++e) {
      p[e] *= inv;
      atomicAdd(&psh[e], p[e]);  // LDS scope
    }
    int i0 = 0;
#pragma unroll
    for (int e = 1; e < 8; ++e) if (p[e] > p[i0]) i0 = e;
    int i1 = (i0 == 0) ? 1 : 0;
#pragma unroll
    for (int e = 0; e < 8; ++e) if (e != i0 && p[e] > p[i1]) i1 = e;
    float ps = p[i0] + p[i1] + 1e-10f;
    float q0 = p[i0] / ps, q1 = p[i1] / ps;
    int l0 = atomicAdd(&h_cnt[i0], 1);  // LDS scope
    int l1 = atomicAdd(&h_cnt[i1], 1);
    tok_bkt[i0 * (RB_NUM * 16) + rb * 16 + l0] = t * 2 + 0;
    p_bkt[i0 * (RB_NUM * 16) + rb * 16 + l0] = q0;
    tok_bkt[i1 * (RB_NUM * 16) + rb * 16 + l1] = t * 2 + 1;
    p_bkt[i1 * (RB_NUM * 16) + rb * 16 + l1] = q1;
  }
  __syncthreads();
  if (tid < E_NUM) {
    cnt_blk[rb * 8 + tid] = h_cnt[tid];   // plain stores, fully owned
    psum_blk[rb * 8 + tid] = psh[tid];
  }
}

// ---------- grouped gate/up GEMM (256 tok x 64 h tile, G+U fused) ----------
// z==8: single loss block; z<8: expert GEMM with wave-shuffle-scan row lookup
__global__ void __launch_bounds__(256, 2) moe_gateup_kernel(
    const short* __restrict__ xb, const short* __restrict__ wg,
    const short* __restrict__ wu, const int* __restrict__ cnt_blk,
    const int* __restrict__ tok_bkt, const float* __restrict__ p_bkt,
    const float* __restrict__ psum_blk, short* __restrict__ act,
    float* __restrict__ out_loss) {
  int e = blockIdx.z;
  int tid = threadIdx.x;

  if (e == 8) {  // load-balance loss
    if (blockIdx.x || blockIdx.y) return;
    __shared__ float sums[8];
    if (tid < 8) sums[tid] = 0.f;
    __syncthreads();
#pragma unroll
    for (int ee = 0; ee < 8; ++ee)
      atomicAdd(&sums[ee], psum_blk[tid * 8 + ee]);
    __syncthreads();
    if (tid == 0) {
      float lb = 0.f;
#pragma unroll
      for (int ee = 0; ee < 8; ++ee) {
        float pe = sums[ee] / (float)N_TOK;
        lb += pe * logf(pe * 8.f + 1e-10f);
      }
      out_loss[0] = 8.f * lb;
    }
    return;
  }

  __shared__ __align__(16) short As[256 * 64];   // 32 KB
  __shared__ __align__(16) short Bgs[64 * 64];   // 8 KB
  __shared__ __align__(16) short Bus[64 * 64];   // 8 KB
  __shared__ int scan[256];
  __shared__ int wsum[4];
  __shared__ int s_row[256];
  __shared__ float s_pr[256];

  int lane = tid & 63, wid = tid >> 6;

  // inclusive prefix scan via wave shuffles (1 barrier)
  {
    int c = cnt_blk[tid * 8 + e];
#pragma unroll
    for (int ofs = 1; ofs < 64; ofs <<= 1) {
      int v = __shfl_up(c, ofs);
      if (lane >= ofs) c += v;
    }
    if (lane == 63) wsum[wid] = c;
    __syncthreads();
    int pre = 0;
#pragma unroll
    for (int w = 0; w < 4; ++w) pre += (w < wid) ? wsum[w] : 0;
    scan[tid] = c + pre;
    __syncthreads();
  }
  int n_e = scan[255];
  int rt = blockIdx.y;
  if (rt * 256 >= n_e) return;
  int h0 = blockIdx.x * 64;

  {
    int r = rt * 256 + tid;
    int srow = -1;
    float spr = 0.f;
    if (r < n_e) {
      int lo = 0, hi = 255;  // smallest b with scan[b] > r
      while (lo < hi) { int mid = (lo + hi) >> 1; if (scan[mid] > r) hi = mid; else lo = mid + 1; }
      int prev = lo ? scan[lo - 1] : 0;
      int idx = e * (RB_NUM * 16) + lo * 16 + (r - prev);
      srow = tok_bkt[idx];
      spr = p_bkt[idx];
    }
    s_row[tid] = srow;
    s_pr[tid] = spr;
  }
  __syncthreads();

  int cg = (lane & 7) ^ (lane >> 3);  // swizzled global chunk for this lane
  const short* baseA[8];
  const short* baseB[4];
  short* ldsA = As + (size_t)wid * 64 * 64;
  short* ldsB;
#pragma unroll
  for (int jj = 0; jj < 8; ++jj) {
    int r = wid * 64 + jj * 8 + (lane >> 3);
    int row = s_row[r];
    int t = (row < 0) ? 0 : (row >> 1);
    baseA[jj] = xb + (size_t)t * D_DIM + cg * 8;
  }
  {
    const short* wB = ((wid & 2) ? wu : wg) + (size_t)e * H_DIM * D_DIM;
    int rb = (wid & 1) * 32;
    ldsB = ((wid & 2) ? Bus : Bgs) + rb * 64;
#pragma unroll
    for (int jj = 0; jj < 4; ++jj) {
      int h = h0 + rb + jj * 8 + (lane >> 3);
      baseB[jj] = wB + (size_t)h * D_DIM + cg * 8;
    }
  }

  int ml = lane & 15, quad = lane >> 4;
  int m0w = wid * 64;
  f32x4 accG[4][4], accU[4][4];
#pragma unroll
  for (int mf = 0; mf < 4; ++mf)
#pragma unroll
    for (int nf = 0; nf < 4; ++nf) {
      accG[mf][nf] = (f32x4){0, 0, 0, 0};
      accU[mf][nf] = (f32x4){0, 0, 0, 0};
    }

  for (int kt = 0; kt < D_DIM / 64; ++kt) {
    int kb = kt * 64;
#pragma unroll
    for (int jj = 0; jj < 8; ++jj)
      llds16(baseA[jj] + kb, ldsA + jj * 8 * 64);
#pragma unroll
    for (int jj = 0; jj < 4; ++jj)
      llds16(baseB[jj] + kb, ldsB + jj * 8 * 64);
    __syncthreads();
#pragma unroll
    for (int ks = 0; ks < 2; ++ks) {
      int cs = ((quad + ks * 4) ^ (ml & 7)) * 8;
      short8 a[4], bg[4], bu[4];
#pragma unroll
      for (int mf = 0; mf < 4; ++mf)
        a[mf] = *(const short8*)&As[(m0w + mf * 16 + ml) * 64 + cs];
#pragma unroll
      for (int nf = 0; nf < 4; ++nf) {
        bg[nf] = *(const short8*)&Bgs[(nf * 16 + ml) * 64 + cs];
        bu[nf] = *(const short8*)&Bus[(nf * 16 + ml) * 64 + cs];
      }
#pragma unroll
      for (int mf = 0; mf < 4; ++mf)
#pragma unroll
        for (int nf = 0; nf < 4; ++nf) {
          accG[mf][nf] = __builtin_amdgcn_mfma_f32_16x16x32_bf16(a[mf], bg[nf], accG[mf][nf], 0, 0, 0);
          accU[mf][nf] = __builtin_amdgcn_mfma_f32_16x16x32_bf16(a[mf], bu[nf], accU[mf][nf], 0, 0, 0);
        }
    }
    __syncthreads();
  }

#pragma unroll
  for (int mf = 0; mf < 4; ++mf)
#pragma unroll
    for (int r = 0; r < 4; ++r) {
      int rl = m0w + mf * 16 + quad * 4 + r;
      int arow = s_row[rl];
      if (arow >= 0) {
        float pr = s_pr[rl];
#pragma unroll
        for (int nf = 0; nf < 4; ++nf) {
          float g = accG[mf][nf][r], u = accU[mf][nf][r];
          float val = pr * (g / (1.f + __expf(-g))) * u;
          act[(size_t)arow * H_DIM + h0 + nf * 16 + ml] = f2bs(val);
        }
      }
    }
}

// ---------- down GEMM: partial[ksb][t][d] = act-slice @ wd (plain stores) ----------
// 128x128 tile, Ksplit=4 across blockIdx.z
__global__ void __launch_bounds__(256, 3) down_kernel(
    const short* __restrict__ act, const short* __restrict__ wd,
    float* __restrict__ partial) {
  __shared__ __align__(16) short As[128 * 64];  // 16 KB
  __shared__ __align__(16) short Bs[128 * 64];  // 16 KB
  int d0 = blockIdx.x * 128;
  int t0 = blockIdx.y * 128;
  int ksb = blockIdx.z;  // kt range [ksb*16, ksb*16+16)
  int tid = threadIdx.x, lane = tid & 63, wid = tid >> 6;
  int cg = (lane & 7) ^ (lane >> 3);

  const short* baseA[4];
  const short* baseB[4];
  short* ldsA = As + (size_t)wid * 32 * 64;
  short* ldsB = Bs + (size_t)wid * 32 * 64;
#pragma unroll
  for (int jj = 0; jj < 4; ++jj) {
    int r = wid * 32 + jj * 8 + (lane >> 3);
    baseA[jj] = act + (size_t)(2 * (t0 + r)) * H_DIM + cg * 8;
    int d = d0 + wid * 32 + jj * 8 + (lane >> 3);
    baseB[jj] = wd + (size_t)d * H_DIM + cg * 8;
  }

  int ml = lane & 15, quad = lane >> 4;
  int m0w = (wid & 1) * 64, n0w = (wid >> 1) * 64;
  f32x4 acc[4][4];
#pragma unroll
  for (int mf = 0; mf < 4; ++mf)
#pragma unroll
    for (int nf = 0; nf < 4; ++nf) acc[mf][nf] = (f32x4){0, 0, 0, 0};

  for (int kt = ksb * 16; kt < ksb * 16 + 16; ++kt) {
    size_t offA = (size_t)(kt & 1) * H_DIM + (kt >> 1) * 64;
    int offB = (kt >> 1) * 64;
#pragma unroll
    for (int jj = 0; jj < 4; ++jj) {
      llds16(baseA[jj] + offA, ldsA + jj * 8 * 64);
      llds16(baseB[jj] + offB, ldsB + jj * 8 * 64);
    }
    __syncthreads();
#pragma unroll
    for (int ks = 0; ks < 2; ++ks) {
      int cs = ((quad + ks * 4) ^ (ml & 7)) * 8;
      short8 a[4], b[4];
#pragma unroll
      for (int mf = 0; mf < 4; ++mf)
        a[mf] = *(const short8*)&As[(m0w + mf * 16 + ml) * 64 + cs];
#pragma unroll
      for (int nf = 0; nf < 4; ++nf)
        b[nf] = *(const short8*)&Bs[(n0w + nf * 16 + ml) * 64 + cs];
#pragma unroll
      for (int mf = 0; mf < 4; ++mf)
#pragma unroll
        for (int nf = 0; nf < 4; ++nf)
          acc[mf][nf] = __builtin_amdgcn_mfma_f32_16x16x32_bf16(a[mf], b[nf], acc[mf][nf], 0, 0, 0);
    }
    __syncthreads();
  }

  float* pout = partial + (size_t)ksb * N_TOK * D_DIM;
#pragma unroll
  for (int mf = 0; mf < 4; ++mf)
#pragma unroll
    for (int r = 0; r < 4; ++r) {
      int t = t0 + m0w + mf * 16 + quad * 4 + r;
#pragma unroll
      for (int nf = 0; nf < 4; ++nf)
        pout[(size_t)t * D_DIM + d0 + n0w + nf * 16 + ml] = acc[mf][nf][r];
    }
}

// ---------- split-K reduce: out = sum of 4 partials ----------
__global__ void __launch_bounds__(256) reduce_kernel(
    const float* __restrict__ partial, float* __restrict__ out) {
  int i = blockIdx.x * 256 + threadIdx.x;  // float4 index
  const int Q = N_TOK * D_DIM / 4;
  const float4* p = (const float4*)partial;
  float4 a = p[i], b = p[i + Q], c = p[i + 2 * Q], d = p[i + 3 * Q];
  float4 r = {a.x + b.x + c.x + d.x, a.y + b.y + c.y + d.y,
              a.z + b.z + c.z + d.z, a.w + b.w + c.w + d.w};
  ((float4*)out)[i] = r;
}

extern "C" void kernel_launch(void* const* d_in, const int* in_sizes, int n_in,
                              void* d_out, int out_size, void* d_ws, size_t ws_size,
                              hipStream_t stream) {
  const float* x = (const float*)d_in[0];
  const float* wr = (const float*)d_in[1];
  const float* wg = (const float*)d_in[2];
  const float* wu = (const float*)d_in[3];
  const float* wd = (const float*)d_in[4];
  float* out = (float*)d_out;

  char* ws = (char*)d_ws;
  size_t off = 0;
  auto alloc = [&](size_t bytes) {
    char* p = ws + off;
    off += (bytes + 255) & ~(size_t)255;
    return p;
  };
  short* xb = (short*)alloc((size_t)N_TOK * D_DIM * 2);
  short* wgb = (short*)alloc((size_t)E_NUM * H_DIM * D_DIM * 2);  // [e*H+h][d]
  short* wub = (short*)alloc((size_t)E_NUM * H_DIM * D_DIM * 2);
  short* wdb = (short*)alloc((size_t)D_DIM * H_DIM * 2);          // [d][h]
  short* act = (short*)alloc((size_t)N_TOK * 2 * H_DIM * 2);      // [2t+slot][H]
  float* partial = (float*)alloc((size_t)4 * N_TOK * D_DIM * 4);  // split-K partials
  int* cnt_blk = (int*)alloc((size_t)RB_NUM * E_NUM * 4);
  int* tok_bkt = (int*)alloc((size_t)E_NUM * RB_NUM * 16 * 4);
  float* p_bkt = (float*)alloc((size_t)E_NUM * RB_NUM * 16 * 4);
  float* psum_blk = (float*)alloc((size_t)RB_NUM * E_NUM * 4);

  prep_router_kernel<<<RB_NUM + TP_NUM, 256, 0, stream>>>(
      wg, wu, wd, x, wr, wgb, wub, wdb, xb, cnt_blk, tok_bkt, p_bkt, psum_blk);
  moe_gateup_kernel<<<dim3(H_DIM / 64, N_TOK / 256, E_NUM + 1), 256, 0, stream>>>(
      xb, wgb, wub, cnt_blk, tok_bkt, p_bkt, psum_blk, act,
      out + (size_t)N_TOK * D_DIM);
  down_kernel<<<dim3(D_DIM / 128, N_TOK / 128, 4), 256, 0, stream>>>(
      act, wdb, partial);
  reduce_kernel<<<N_TOK * D_DIM / 4 / 256, 256, 0, stream>>>(partial, out);
}